// Round 8
// baseline (228.784 us; speedup 1.0000x reference)
//
#include <hip/hip_runtime.h>
#include <hip/hip_bf16.h>

#define B_ 2
#define S_ 2048
#define D_ 1024
#define H_ 16
#define HD_ 64

// Q is pre-scaled by 0.125 * log2(e) at projection time; attention runs in
// log2 domain: p = exp2(qk_scaled); mask folded into V and rowsum weights
// w_k = exp2((mask_k - 1) * 10000 * log2(e)) in {0,1}.
#define QSCALE 0.18033688f
#define MLOG2E 14426.950408f

typedef __attribute__((ext_vector_type(8))) short bf16x8;
typedef __attribute__((ext_vector_type(4))) short short4v;
typedef __attribute__((ext_vector_type(4))) float floatx4;

static __device__ __forceinline__ float bf2f(short u) {
  union { float f; unsigned int i; } c;
  c.i = ((unsigned int)(unsigned short)u) << 16;
  return c.f;
}
static __device__ __forceinline__ short f2bf(float f) {
  union { float f; unsigned int i; } c; c.f = f;
  unsigned int r = c.i + 0x7FFFu + ((c.i >> 16) & 1u);
  return (short)(r >> 16);
}
static __device__ __forceinline__ short f2bf_fast(float f) {  // round-half-up
  union { float f; unsigned int i; } c; c.f = f;
  return (short)((c.i + 0x8000u) >> 16);
}

static __device__ __forceinline__ void gld_lds16(const void* g, void* l) {
  __builtin_amdgcn_global_load_lds(
      (const __attribute__((address_space(1))) unsigned int*)g,
      (__attribute__((address_space(3))) unsigned int*)l, 16, 0, 0);
}

// ---------------- prep: weight transposes (z<4) + hs fp32->bf16 (z==4) ------
__global__ __launch_bounds__(256)
void prep(const float* __restrict__ w0, const float* __restrict__ w1,
          const float* __restrict__ w2, const float* __restrict__ w3,
          const float* __restrict__ hs, short* __restrict__ WT,
          short* __restrict__ Xb) {
  const int z = blockIdx.z;
  if (z < 4) {
    __shared__ short t[64][65];
    const float* src = z == 0 ? w0 : z == 1 ? w1 : z == 2 ? w2 : w3;
    short* dst = WT + (size_t)z * D_ * D_;
    const int tx = threadIdx.x & 63, ty = threadIdx.x >> 6;
    const int r0 = blockIdx.y * 64, c0 = blockIdx.x * 64;
    for (int r = ty; r < 64; r += 4)
      t[r][tx] = f2bf(src[(size_t)(r0 + r) * D_ + c0 + tx]);
    __syncthreads();
    for (int r = ty; r < 64; r += 4)
      dst[(size_t)(c0 + r) * D_ + r0 + tx] = t[tx][r];
  } else {
    const int bid = blockIdx.y * 16 + blockIdx.x;
    const float4* in4 = (const float4*)hs;
    short4v* out4 = (short4v*)Xb;
#pragma unroll
    for (int i = 0; i < 16; i++) {
      const int idx = bid * 4096 + i * 256 + threadIdx.x;
      const float4 v = in4[idx];
      short4v o;
      o[0] = f2bf(v.x); o[1] = f2bf(v.y); o[2] = f2bf(v.z); o[3] = f2bf(v.w);
      out4[idx] = o;
    }
  }
}

// ---------------- fused QKV projection (single launch) ----------------
// widx 0/1 (Q,K): operand-swapped MFMA -> C^T, b64 stores to [B,H,S,HD].
// widx 2 (V): normal orientation -> V^T [B,H,HD,S], scaled by mask weight w.
__global__ __launch_bounds__(256, 3)
void gemm_qkv(const short* __restrict__ X, const short* __restrict__ WT,
              const float* __restrict__ qb, const float* __restrict__ kb,
              const float* __restrict__ vb, const float* __restrict__ mask,
              short* __restrict__ Qo, short* __restrict__ Ko,
              short* __restrict__ Vt) {
  __shared__ __align__(16) short As[128 * 32];
  __shared__ __align__(16) short Bs[128 * 32];
  const int tid = threadIdx.x;
  const int wave = tid >> 6, lane = tid & 63;
  const int col = lane & 15, quad = lane >> 4;
  const int m0 = blockIdx.x * 128;          // seq offset
  const int nt = blockIdx.y;
  const int widx = nt >> 3;                 // 0=Q 1=K 2=V
  const int n1 = (nt & 7) * 128;            // feature offset
  const short* Bsrc = WT + (size_t)widx * D_ * D_ + (size_t)n1 * D_;
  const int b = m0 >> 11;

  const int srow = tid >> 2;
  const int skcol = (tid & 3) * 8;
  const short* ga = X + (size_t)(m0 + srow) * D_ + skcol;
  const short* gb = Bsrc + (size_t)srow * D_ + skcol;
  short* la = As + tid * 8;
  short* lb = Bs + tid * 8;

  floatx4 acc[4][4];
#pragma unroll
  for (int i = 0; i < 4; i++)
#pragma unroll
    for (int j = 0; j < 4; j++) acc[i][j] = floatx4{0.f, 0.f, 0.f, 0.f};

  if (widx < 2) {  // ---- Q/K: swapped operands -> C^T ----
    const int wseq = (wave >> 1) * 64;
    const int wfeat = (wave & 1) * 64;
    for (int k0 = 0; k0 < D_; k0 += 32) {
      gld_lds16(ga, la);
      gld_lds16(ga + 64 * D_, la + 2048);
      gld_lds16(gb, lb);
      gld_lds16(gb + 64 * D_, lb + 2048);
      ga += 32; gb += 32;
      __syncthreads();
      bf16x8 xf[4], wf[4];
#pragma unroll
      for (int j = 0; j < 4; j++)
        xf[j] = *(const bf16x8*)(As + (wseq + j * 16 + col) * 32 + quad * 8);
#pragma unroll
      for (int i = 0; i < 4; i++)
        wf[i] = *(const bf16x8*)(Bs + (wfeat + i * 16 + col) * 32 + quad * 8);
#pragma unroll
      for (int i = 0; i < 4; i++)
#pragma unroll
        for (int j = 0; j < 4; j++)
          acc[i][j] = __builtin_amdgcn_mfma_f32_16x16x32_bf16(wf[i], xf[j],
                                                              acc[i][j], 0, 0, 0);
      __syncthreads();
    }
    const float* bias = widx == 0 ? qb : kb;
    short* dst = widx == 0 ? Qo : Ko;
    const float scale = widx == 0 ? QSCALE : 1.0f;
#pragma unroll
    for (int i = 0; i < 4; i++) {
      const int nf = n1 + wfeat + i * 16 + quad * 4;  // 4 consecutive features
      const int h = nf >> 6, hd = nf & 63;
      const float4 bv = *(const float4*)(bias + nf);
#pragma unroll
      for (int j = 0; j < 4; j++) {
        const int s = (m0 + wseq + j * 16 + col) & (S_ - 1);
        short4v pk;
        pk[0] = f2bf((acc[i][j][0] + bv.x) * scale);
        pk[1] = f2bf((acc[i][j][1] + bv.y) * scale);
        pk[2] = f2bf((acc[i][j][2] + bv.z) * scale);
        pk[3] = f2bf((acc[i][j][3] + bv.w) * scale);
        *(short4v*)(dst + ((size_t)(b * H_ + h) * S_ + s) * HD_ + hd) = pk;
      }
    }
  } else {  // ---- V: normal orientation, mask-weighted V^T output ----
    const int wrow = (wave & 1) * 64;
    const int wcol = (wave >> 1) * 64;
    for (int k0 = 0; k0 < D_; k0 += 32) {
      gld_lds16(ga, la);
      gld_lds16(ga + 64 * D_, la + 2048);
      gld_lds16(gb, lb);
      gld_lds16(gb + 64 * D_, lb + 2048);
      ga += 32; gb += 32;
      __syncthreads();
      bf16x8 af[4], bfr[4];
#pragma unroll
      for (int i = 0; i < 4; i++)
        af[i] = *(const bf16x8*)(As + (wrow + i * 16 + col) * 32 + quad * 8);
#pragma unroll
      for (int j = 0; j < 4; j++)
        bfr[j] = *(const bf16x8*)(Bs + (wcol + j * 16 + col) * 32 + quad * 8);
#pragma unroll
      for (int i = 0; i < 4; i++)
#pragma unroll
        for (int j = 0; j < 4; j++)
          acc[i][j] = __builtin_amdgcn_mfma_f32_16x16x32_bf16(af[i], bfr[j],
                                                              acc[i][j], 0, 0, 0);
      __syncthreads();
    }
    float bv[4];
#pragma unroll
    for (int j = 0; j < 4; j++) bv[j] = vb[n1 + wcol + j * 16 + col];
    const float* mkb = mask + (size_t)b * S_;
#pragma unroll
    for (int i = 0; i < 4; i++) {
      const int s = (m0 + wrow + i * 16 + quad * 4) & (S_ - 1);
      const float4 mv = *(const float4*)(mkb + s);
      float w[4];
      w[0] = exp2f((mv.x - 1.0f) * MLOG2E);
      w[1] = exp2f((mv.y - 1.0f) * MLOG2E);
      w[2] = exp2f((mv.z - 1.0f) * MLOG2E);
      w[3] = exp2f((mv.w - 1.0f) * MLOG2E);
#pragma unroll
      for (int j = 0; j < 4; j++) {
        const int nl = n1 + wcol + j * 16 + col;
        const int h = nl >> 6, hd = nl & 63;
        short4v pk;
#pragma unroll
        for (int r = 0; r < 4; r++) pk[r] = f2bf((acc[i][j][r] + bv[j]) * w[r]);
        *(short4v*)(Vt + ((size_t)(b * H_ + h) * HD_ + hd) * S_ + s) = pk;
      }
    }
  }
}

// ---------------- flash attention: g=4 (64 q-rows/wave), ILP-deep ----------
// grid 256 linear (1 block/CU), XCD swizzle: all 8 q-tiles of one (b,h) on
// one XCD. 4 waves x 64 q-rows = 256 rows/block; 32 dbuf K/V iters.
// QK as S^T (mfma(kf,qf)); P strips ping-pong [wave][g&1][16][68] (stride 68
// => bank 2*col, conflict-free); pf for all 4 g held in regs so vf is read
// once per iter. Mask folded into V + Ws rowsum weights.
__global__ __launch_bounds__(256, 1)
void attn(const short* __restrict__ Q, const short* __restrict__ K,
          const short* __restrict__ Vt, const float* __restrict__ mask,
          short* __restrict__ ctx) {
  __shared__ __align__(16) short Ks[2][4096];      // 16 KB
  __shared__ __align__(16) short Vs[2][4096];      // 16 KB
  __shared__ __align__(16) short P[4][2][16][68];  // 17 KB ping-pong strips
  __shared__ __align__(16) short Ws[S_];           // 4 KB mask weights (bf16)
  const int tid = threadIdx.x, wave = tid >> 6, lane = tid & 63;
  const int col = lane & 15, quad = lane >> 4;
  const int lin = blockIdx.x;
  const int qt = (lin >> 3) & 7;
  const int bh = (lin & 7) | ((lin >> 6) << 3);
  const int h = bh & 15, b = bh >> 4;
  const short* Qh = Q + (size_t)bh * S_ * HD_;
  const short* Kh = K + (size_t)bh * S_ * HD_;
  const short* Vh = Vt + (size_t)bh * HD_ * S_;
  const float* mk = mask + (size_t)b * S_;
  const int q0 = qt * 256 + wave * 64;

  // staging chunk mapping: row r, slot c stores source chunk c^(r&7)
  const int r1 = tid >> 3, c1 = (tid & 7) ^ (r1 & 7);
  const int r2 = r1 + 32,  c2 = (tid & 7) ^ (r2 & 7);
  const int swz = quad ^ (col & 7);  // fragment read slot

  // prologue: stage tile 0 into buffer 0
  gld_lds16(Kh + (size_t)r1 * HD_ + c1 * 8, &Ks[0][tid * 8]);
  gld_lds16(Kh + (size_t)r2 * HD_ + c2 * 8, &Ks[0][(tid + 256) * 8]);
  gld_lds16(Vh + (size_t)r1 * S_ + c1 * 8, &Vs[0][tid * 8]);
  gld_lds16(Vh + (size_t)r2 * S_ + c2 * 8, &Vs[0][(tid + 256) * 8]);

  // mask weight table: w = exp2((m-1)*MLOG2E) in {0,1}
  for (int i = tid; i < S_; i += 256)
    Ws[i] = f2bf(exp2f((mk[i] - 1.0f) * MLOG2E));

  bf16x8 qf[4][2];
#pragma unroll
  for (int g = 0; g < 4; g++) {
    const short* qp = Qh + (size_t)(q0 + g * 16 + col) * HD_;
    qf[g][0] = *(const bf16x8*)(qp + quad * 8);
    qf[g][1] = *(const bf16x8*)(qp + 32 + quad * 8);
  }

  floatx4 acc[4][4], rsacc[4];
#pragma unroll
  for (int g = 0; g < 4; g++) {
    rsacc[g] = floatx4{0.f, 0.f, 0.f, 0.f};
#pragma unroll
    for (int d = 0; d < 4; d++) acc[g][d] = floatx4{0.f, 0.f, 0.f, 0.f};
  }

  __syncthreads();  // tile 0 + w table staged

  for (int it = 0; it < S_ / 64; it++) {
    const int buf = it & 1;
    const int kt = it * 64;
    if (it + 1 < S_ / 64) {  // issue next tile's staging
      const int kn = kt + 64;
      gld_lds16(Kh + (size_t)(kn + r1) * HD_ + c1 * 8, &Ks[buf ^ 1][tid * 8]);
      gld_lds16(Kh + (size_t)(kn + r2) * HD_ + c2 * 8, &Ks[buf ^ 1][(tid + 256) * 8]);
      gld_lds16(Vh + (size_t)r1 * S_ + kn + c1 * 8, &Vs[buf ^ 1][tid * 8]);
      gld_lds16(Vh + (size_t)r2 * S_ + kn + c2 * 8, &Vs[buf ^ 1][(tid + 256) * 8]);
    }

    bf16x8 kf[4][2];
#pragma unroll
    for (int t = 0; t < 4; t++) {
      const short* kp = &Ks[buf][(t * 16 + col) * 64];
      kf[t][0] = *(const bf16x8*)(kp + swz * 8);
      kf[t][1] = *(const bf16x8*)(kp + (swz ^ 4) * 8);
    }

    bf16x8 pf[4][2];
    bf16x8 wf0 = *(const bf16x8*)&Ws[kt + quad * 8];        // broadcast
    bf16x8 wf1 = *(const bf16x8*)&Ws[kt + 32 + quad * 8];
#pragma unroll
    for (int g = 0; g < 4; g++) {
      const int pb = g & 1;  // ping-pong strip
#pragma unroll
      for (int t = 0; t < 4; t++) {
        floatx4 z = floatx4{0.f, 0.f, 0.f, 0.f};
        z = __builtin_amdgcn_mfma_f32_16x16x32_bf16(kf[t][0], qf[g][0], z, 0, 0, 0);
        z = __builtin_amdgcn_mfma_f32_16x16x32_bf16(kf[t][1], qf[g][1], z, 0, 0, 0);
        short4v pk;
#pragma unroll
        for (int r = 0; r < 4; r++) pk[r] = f2bf_fast(exp2f(z[r]));
        *(short4v*)&P[wave][pb][col][t * 16 + quad * 4] = pk;
      }
#pragma unroll
      for (int kk = 0; kk < 2; kk++) {
        const short4v p0 = *(const short4v*)&P[wave][pb][col][kk * 32 + quad * 8];
        const short4v p1 = *(const short4v*)&P[wave][pb][col][kk * 32 + quad * 8 + 4];
        bf16x8 pv;
        pv[0] = p0[0]; pv[1] = p0[1]; pv[2] = p0[2]; pv[3] = p0[3];
        pv[4] = p1[0]; pv[5] = p1[1]; pv[6] = p1[2]; pv[7] = p1[3];
        pf[g][kk] = pv;
      }
      rsacc[g] = __builtin_amdgcn_mfma_f32_16x16x32_bf16(wf0, pf[g][0], rsacc[g], 0, 0, 0);
      rsacc[g] = __builtin_amdgcn_mfma_f32_16x16x32_bf16(wf1, pf[g][1], rsacc[g], 0, 0, 0);
    }

#pragma unroll
    for (int d = 0; d < 4; d++) {
      const short* vp = &Vs[buf][(d * 16 + col) * 64];
      const bf16x8 vf0 = *(const bf16x8*)(vp + swz * 8);
      const bf16x8 vf1 = *(const bf16x8*)(vp + (swz ^ 4) * 8);
#pragma unroll
      for (int g = 0; g < 4; g++) {
        acc[g][d] = __builtin_amdgcn_mfma_f32_16x16x32_bf16(vf0, pf[g][0], acc[g][d], 0, 0, 0);
        acc[g][d] = __builtin_amdgcn_mfma_f32_16x16x32_bf16(vf1, pf[g][1], acc[g][d], 0, 0, 0);
      }
    }
    __syncthreads();  // compute reads done; next staging landed
  }

  // epilogue: ctx^T in regs -> lane col is q-row, hd = d*16 + quad*4 + r
#pragma unroll
  for (int g = 0; g < 4; g++) {
    const float inv = 1.0f / (rsacc[g][0] + 1e-30f);
    const size_t row = (size_t)b * S_ + q0 + g * 16 + col;
#pragma unroll
    for (int d = 0; d < 4; d++) {
      short4v o;
#pragma unroll
      for (int r = 0; r < 4; r++) o[r] = f2bf(acc[g][d][r] * inv);
      *(short4v*)(ctx + row * D_ + h * HD_ + d * 16 + quad * 4) = o;
    }
  }
}

// ---------------- output projection: 64x128 tile, grid 512 (2 blocks/CU) ----
__global__ __launch_bounds__(256, 2)
void gemm_out(const short* __restrict__ X, const short* __restrict__ WT,
              const float* __restrict__ ob, float* __restrict__ out) {
  __shared__ __align__(16) short As[64 * 32];    // 4 KB
  __shared__ __align__(16) short Bs[128 * 32];   // 8 KB
  const int tid = threadIdx.x;
  const int wave = tid >> 6, lane = tid & 63;
  const int col = lane & 15, quad = lane >> 4;
  const int m0 = blockIdx.x * 64;
  const int n0 = blockIdx.y * 128;
  const short* Bsrc = WT + (size_t)n0 * D_;
  const int wrow = (wave & 1) * 32;
  const int wcol = (wave >> 1) * 64;

  floatx4 acc[2][4];
#pragma unroll
  for (int i = 0; i < 2; i++)
#pragma unroll
    for (int j = 0; j < 4; j++) acc[i][j] = floatx4{0.f, 0.f, 0.f, 0.f};

  const int arow = tid >> 2, akcol = (tid & 3) * 8;
  const short* ga = X + (size_t)(m0 + arow) * D_ + akcol;
  const short* gb = Bsrc + (size_t)arow * D_ + akcol;
  short* la = As + tid * 8;
  short* lb = Bs + tid * 8;

  for (int k0 = 0; k0 < D_; k0 += 32) {
    gld_lds16(ga, la);
    gld_lds16(gb, lb);
    gld_lds16(gb + 64 * D_, lb + 2048);
    ga += 32; gb += 32;
    __syncthreads();
    bf16x8 af[2], bfr[4];
#pragma unroll
    for (int i = 0; i < 2; i++)
      af[i] = *(const bf16x8*)(As + (wrow + i * 16 + col) * 32 + quad * 8);
#pragma unroll
    for (int j = 0; j < 4; j++)
      bfr[j] = *(const bf16x8*)(Bs + (wcol + j * 16 + col) * 32 + quad * 8);
#pragma unroll
    for (int i = 0; i < 2; i++)
#pragma unroll
      for (int j = 0; j < 4; j++)
        acc[i][j] = __builtin_amdgcn_mfma_f32_16x16x32_bf16(af[i], bfr[j],
                                                            acc[i][j], 0, 0, 0);
    __syncthreads();
  }

  float bv[4];
#pragma unroll
  for (int j = 0; j < 4; j++) bv[j] = ob[n0 + wcol + j * 16 + col];

#pragma unroll
  for (int i = 0; i < 2; i++) {
    const int m = m0 + wrow + i * 16 + quad * 4;
#pragma unroll
    for (int j = 0; j < 4; j++) {
      const int n = n0 + wcol + j * 16 + col;
#pragma unroll
      for (int r = 0; r < 4; r++)
        out[(size_t)(m + r) * D_ + n] = acc[i][j][r] + bv[j];
    }
  }
}

extern "C" void kernel_launch(void* const* d_in, const int* in_sizes, int n_in,
                              void* d_out, int out_size, void* d_ws, size_t ws_size,
                              hipStream_t stream) {
  (void)in_sizes; (void)n_in; (void)out_size; (void)ws_size;
  const float* hs  = (const float*)d_in[0];
  const float* msk = (const float*)d_in[1];
  const float* qw  = (const float*)d_in[2];
  const float* qb  = (const float*)d_in[3];
  const float* kw  = (const float*)d_in[4];
  const float* kb  = (const float*)d_in[5];
  const float* vw  = (const float*)d_in[6];
  const float* vb  = (const float*)d_in[7];
  const float* ow  = (const float*)d_in[8];
  const float* ob  = (const float*)d_in[9];
  float* out = (float*)d_out;
  char* ws = (char*)d_ws;

  short* Xb  = (short*)(ws);                    // bf16 hs (8 MB); reused as Ctx
  short* WT  = (short*)(ws + (8ull  << 20));    // 4 x 1024x1024 bf16 (8 MB)
  short* Qp  = (short*)(ws + (16ull << 20));    // [B,H,S,HD] (8 MB)
  short* Kp  = (short*)(ws + (24ull << 20));    // [B,H,S,HD] (8 MB)
  short* Vtp = (short*)(ws + (32ull << 20));    // [B,H,HD,S] (8 MB)
  short* Ctx = Xb;                              // [B,S,D] bf16 (overlays Xb)

  prep<<<dim3(16, 16, 5), 256, 0, stream>>>(qw, kw, vw, ow, hs, WT, Xb);
  gemm_qkv<<<dim3(32, 24), 256, 0, stream>>>(Xb, WT, qb, kb, vb, msk, Qp, Kp, Vtp);
  attn<<<dim3(256), 256, 0, stream>>>(Qp, Kp, Vtp, msk, Ctx);
  gemm_out<<<dim3(64, 8), 256, 0, stream>>>(Ctx, WT + 3ull * D_ * D_, ob, out);
}

// Round 9
// 197.606 us; speedup vs baseline: 1.1578x; 1.1578x over previous
//
#include <hip/hip_runtime.h>
#include <hip/hip_bf16.h>

#define B_ 2
#define S_ 2048
#define D_ 1024
#define H_ 16
#define HD_ 64

// Q is pre-scaled by 0.125 * log2(e) at projection time; attention runs in
// log2 domain: p = exp2(qk_scaled); mask folded into V and rowsum weights
// w_k = exp2((mask_k - 1) * 10000 * log2(e)) in {0,1}.
#define QSCALE 0.18033688f
#define MLOG2E 14426.950408f

// HW exp2: v_exp_f32 computes 2^x directly. libm exp2f() is an OCML call
// with range handling (~15 VALU ops) — measured as the round 5-8 VALU bloat.
#define EXP2(x) __builtin_amdgcn_exp2f(x)

typedef __attribute__((ext_vector_type(8))) short bf16x8;
typedef __attribute__((ext_vector_type(4))) short short4v;
typedef __attribute__((ext_vector_type(4))) float floatx4;

static __device__ __forceinline__ float bf2f(short u) {
  union { float f; unsigned int i; } c;
  c.i = ((unsigned int)(unsigned short)u) << 16;
  return c.f;
}
static __device__ __forceinline__ short f2bf(float f) {
  union { float f; unsigned int i; } c; c.f = f;
  unsigned int r = c.i + 0x7FFFu + ((c.i >> 16) & 1u);
  return (short)(r >> 16);
}
static __device__ __forceinline__ short f2bf_fast(float f) {  // round-half-up
  union { float f; unsigned int i; } c; c.f = f;
  return (short)((c.i + 0x8000u) >> 16);
}

static __device__ __forceinline__ void gld_lds16(const void* g, void* l) {
  __builtin_amdgcn_global_load_lds(
      (const __attribute__((address_space(1))) unsigned int*)g,
      (__attribute__((address_space(3))) unsigned int*)l, 16, 0, 0);
}

// ---------------- prep: weight transposes (z<4) + hs fp32->bf16 (z==4) ------
__global__ __launch_bounds__(256)
void prep(const float* __restrict__ w0, const float* __restrict__ w1,
          const float* __restrict__ w2, const float* __restrict__ w3,
          const float* __restrict__ hs, short* __restrict__ WT,
          short* __restrict__ Xb) {
  const int z = blockIdx.z;
  if (z < 4) {
    __shared__ short t[64][65];
    const float* src = z == 0 ? w0 : z == 1 ? w1 : z == 2 ? w2 : w3;
    short* dst = WT + (size_t)z * D_ * D_;
    const int tx = threadIdx.x & 63, ty = threadIdx.x >> 6;
    const int r0 = blockIdx.y * 64, c0 = blockIdx.x * 64;
    for (int r = ty; r < 64; r += 4)
      t[r][tx] = f2bf(src[(size_t)(r0 + r) * D_ + c0 + tx]);
    __syncthreads();
    for (int r = ty; r < 64; r += 4)
      dst[(size_t)(c0 + r) * D_ + r0 + tx] = t[tx][r];
  } else {
    const int bid = blockIdx.y * 16 + blockIdx.x;
    const float4* in4 = (const float4*)hs;
    short4v* out4 = (short4v*)Xb;
#pragma unroll
    for (int i = 0; i < 16; i++) {
      const int idx = bid * 4096 + i * 256 + threadIdx.x;
      const float4 v = in4[idx];
      short4v o;
      o[0] = f2bf(v.x); o[1] = f2bf(v.y); o[2] = f2bf(v.z); o[3] = f2bf(v.w);
      out4[idx] = o;
    }
  }
}

// ---------------- fused QKV projection (single launch) ----------------
// widx 0/1 (Q,K): operand-swapped MFMA -> C^T, b64 stores to [B,H,S,HD].
// widx 2 (V): normal orientation -> V^T [B,H,HD,S], scaled by mask weight w.
__global__ __launch_bounds__(256, 2)
void gemm_qkv(const short* __restrict__ X, const short* __restrict__ WT,
              const float* __restrict__ qb, const float* __restrict__ kb,
              const float* __restrict__ vb, const float* __restrict__ mask,
              short* __restrict__ Qo, short* __restrict__ Ko,
              short* __restrict__ Vt) {
  __shared__ __align__(16) short As[128 * 32];
  __shared__ __align__(16) short Bs[128 * 32];
  const int tid = threadIdx.x;
  const int wave = tid >> 6, lane = tid & 63;
  const int col = lane & 15, quad = lane >> 4;
  const int m0 = blockIdx.x * 128;          // seq offset
  const int nt = blockIdx.y;
  const int widx = nt >> 3;                 // 0=Q 1=K 2=V
  const int n1 = (nt & 7) * 128;            // feature offset
  const short* Bsrc = WT + (size_t)widx * D_ * D_ + (size_t)n1 * D_;
  const int b = m0 >> 11;

  const int srow = tid >> 2;
  const int skcol = (tid & 3) * 8;
  const short* ga = X + (size_t)(m0 + srow) * D_ + skcol;
  const short* gb = Bsrc + (size_t)srow * D_ + skcol;
  short* la = As + tid * 8;
  short* lb = Bs + tid * 8;

  floatx4 acc[4][4];
#pragma unroll
  for (int i = 0; i < 4; i++)
#pragma unroll
    for (int j = 0; j < 4; j++) acc[i][j] = floatx4{0.f, 0.f, 0.f, 0.f};

  if (widx < 2) {  // ---- Q/K: swapped operands -> C^T ----
    const int wseq = (wave >> 1) * 64;
    const int wfeat = (wave & 1) * 64;
    for (int k0 = 0; k0 < D_; k0 += 32) {
      gld_lds16(ga, la);
      gld_lds16(ga + 64 * D_, la + 2048);
      gld_lds16(gb, lb);
      gld_lds16(gb + 64 * D_, lb + 2048);
      ga += 32; gb += 32;
      __syncthreads();
      bf16x8 xf[4], wf[4];
#pragma unroll
      for (int j = 0; j < 4; j++)
        xf[j] = *(const bf16x8*)(As + (wseq + j * 16 + col) * 32 + quad * 8);
#pragma unroll
      for (int i = 0; i < 4; i++)
        wf[i] = *(const bf16x8*)(Bs + (wfeat + i * 16 + col) * 32 + quad * 8);
#pragma unroll
      for (int i = 0; i < 4; i++)
#pragma unroll
        for (int j = 0; j < 4; j++)
          acc[i][j] = __builtin_amdgcn_mfma_f32_16x16x32_bf16(wf[i], xf[j],
                                                              acc[i][j], 0, 0, 0);
      __syncthreads();
    }
    const float* bias = widx == 0 ? qb : kb;
    short* dst = widx == 0 ? Qo : Ko;
    const float scale = widx == 0 ? QSCALE : 1.0f;
#pragma unroll
    for (int i = 0; i < 4; i++) {
      const int nf = n1 + wfeat + i * 16 + quad * 4;  // 4 consecutive features
      const int h = nf >> 6, hd = nf & 63;
      const float4 bv = *(const float4*)(bias + nf);
#pragma unroll
      for (int j = 0; j < 4; j++) {
        const int s = (m0 + wseq + j * 16 + col) & (S_ - 1);
        short4v pk;
        pk[0] = f2bf((acc[i][j][0] + bv.x) * scale);
        pk[1] = f2bf((acc[i][j][1] + bv.y) * scale);
        pk[2] = f2bf((acc[i][j][2] + bv.z) * scale);
        pk[3] = f2bf((acc[i][j][3] + bv.w) * scale);
        *(short4v*)(dst + ((size_t)(b * H_ + h) * S_ + s) * HD_ + hd) = pk;
      }
    }
  } else {  // ---- V: normal orientation, mask-weighted V^T output ----
    const int wrow = (wave & 1) * 64;
    const int wcol = (wave >> 1) * 64;
    for (int k0 = 0; k0 < D_; k0 += 32) {
      gld_lds16(ga, la);
      gld_lds16(ga + 64 * D_, la + 2048);
      gld_lds16(gb, lb);
      gld_lds16(gb + 64 * D_, lb + 2048);
      ga += 32; gb += 32;
      __syncthreads();
      bf16x8 af[4], bfr[4];
#pragma unroll
      for (int i = 0; i < 4; i++)
        af[i] = *(const bf16x8*)(As + (wrow + i * 16 + col) * 32 + quad * 8);
#pragma unroll
      for (int j = 0; j < 4; j++)
        bfr[j] = *(const bf16x8*)(Bs + (wcol + j * 16 + col) * 32 + quad * 8);
#pragma unroll
      for (int i = 0; i < 4; i++)
#pragma unroll
        for (int j = 0; j < 4; j++)
          acc[i][j] = __builtin_amdgcn_mfma_f32_16x16x32_bf16(af[i], bfr[j],
                                                              acc[i][j], 0, 0, 0);
      __syncthreads();
    }
    float bv[4];
#pragma unroll
    for (int j = 0; j < 4; j++) bv[j] = vb[n1 + wcol + j * 16 + col];
    const float* mkb = mask + (size_t)b * S_;
#pragma unroll
    for (int i = 0; i < 4; i++) {
      const int s = (m0 + wrow + i * 16 + quad * 4) & (S_ - 1);
      const float4 mv = *(const float4*)(mkb + s);
      float w[4];
      w[0] = EXP2((mv.x - 1.0f) * MLOG2E);
      w[1] = EXP2((mv.y - 1.0f) * MLOG2E);
      w[2] = EXP2((mv.z - 1.0f) * MLOG2E);
      w[3] = EXP2((mv.w - 1.0f) * MLOG2E);
#pragma unroll
      for (int j = 0; j < 4; j++) {
        const int nl = n1 + wcol + j * 16 + col;
        const int h = nl >> 6, hd = nl & 63;
        short4v pk;
#pragma unroll
        for (int r = 0; r < 4; r++) pk[r] = f2bf((acc[i][j][r] + bv[j]) * w[r]);
        *(short4v*)(Vt + ((size_t)(b * H_ + h) * HD_ + hd) * S_ + s) = pk;
      }
    }
  }
}

// ---------------- flash attention: r7 structure + conflict-free P + HW exp2 -
// grid 512 linear; XCD swizzle: all 16 q-tiles of one (b,h) share an XCD.
// 4 waves x 32 q-rows (g=2, 2 blocks/CU = 2 waves/SIMD). dbuf LDS K/V,
// 1 barrier/iter. QK as S^T (mfma(kf,qf)) -> packed b64 P writes; P stride
// 68 (r8-verified: 0 bank conflicts). Mask folded into V + Ws rowsum MFMA.
__global__ __launch_bounds__(256, 2)
void attn(const short* __restrict__ Q, const short* __restrict__ K,
          const short* __restrict__ Vt, const float* __restrict__ mask,
          short* __restrict__ ctx) {
  __shared__ __align__(16) short Ks[2][4096];      // 16 KB
  __shared__ __align__(16) short Vs[2][4096];      // 16 KB
  __shared__ __align__(16) short P[4][2][16][68];  // 17 KB (stride 68: 0 conflicts, r8)
  __shared__ __align__(16) short Ws[S_];           // 4 KB mask weights (bf16)
  const int tid = threadIdx.x, wave = tid >> 6, lane = tid & 63;
  const int col = lane & 15, quad = lane >> 4;
  const int lin = blockIdx.x;
  const int qt = (lin >> 3) & 15;
  const int gi = (lin & 7) + ((lin >> 7) << 3);
  const int h = gi & 15, b = gi >> 4;
  const short* Qh = Q + (size_t)(b * H_ + h) * S_ * HD_;
  const short* Kh = K + (size_t)(b * H_ + h) * S_ * HD_;
  const short* Vh = Vt + (size_t)(b * H_ + h) * HD_ * S_;
  const float* mk = mask + (size_t)b * S_;
  const int q0 = qt * 128 + wave * 32;

  // staging chunk mapping: row r, slot c stores source chunk c^(r&7)
  const int r1 = tid >> 3, c1 = (tid & 7) ^ (r1 & 7);
  const int r2 = r1 + 32,  c2 = (tid & 7) ^ (r2 & 7);
  const int swz = quad ^ (col & 7);  // fragment read slot

  // prologue: stage tile 0 into buffer 0
  gld_lds16(Kh + (size_t)r1 * HD_ + c1 * 8, &Ks[0][tid * 8]);
  gld_lds16(Kh + (size_t)r2 * HD_ + c2 * 8, &Ks[0][(tid + 256) * 8]);
  gld_lds16(Vh + (size_t)r1 * S_ + c1 * 8, &Vs[0][tid * 8]);
  gld_lds16(Vh + (size_t)r2 * S_ + c2 * 8, &Vs[0][(tid + 256) * 8]);

  // mask weight table: w = exp2((m-1)*MLOG2E) in {0,1}
  for (int i = tid; i < S_; i += 256)
    Ws[i] = f2bf(EXP2((mk[i] - 1.0f) * MLOG2E));

  bf16x8 qf[2][2];
#pragma unroll
  for (int g = 0; g < 2; g++) {
    const short* qp = Qh + (size_t)(q0 + g * 16 + col) * HD_;
    qf[g][0] = *(const bf16x8*)(qp + quad * 8);
    qf[g][1] = *(const bf16x8*)(qp + 32 + quad * 8);
  }

  floatx4 acc[2][4], rsacc[2];
#pragma unroll
  for (int g = 0; g < 2; g++) {
    rsacc[g] = floatx4{0.f, 0.f, 0.f, 0.f};
#pragma unroll
    for (int d = 0; d < 4; d++) acc[g][d] = floatx4{0.f, 0.f, 0.f, 0.f};
  }

  __syncthreads();  // tile 0 + w table staged

  for (int it = 0; it < S_ / 64; it++) {
    const int buf = it & 1;
    const int kt = it * 64;
    if (it + 1 < S_ / 64) {  // issue next tile's staging
      const int kn = kt + 64;
      gld_lds16(Kh + (size_t)(kn + r1) * HD_ + c1 * 8, &Ks[buf ^ 1][tid * 8]);
      gld_lds16(Kh + (size_t)(kn + r2) * HD_ + c2 * 8, &Ks[buf ^ 1][(tid + 256) * 8]);
      gld_lds16(Vh + (size_t)r1 * S_ + kn + c1 * 8, &Vs[buf ^ 1][tid * 8]);
      gld_lds16(Vh + (size_t)r2 * S_ + kn + c2 * 8, &Vs[buf ^ 1][(tid + 256) * 8]);
    }

    bf16x8 kf[4][2];
#pragma unroll
    for (int t = 0; t < 4; t++) {
      const short* kp = &Ks[buf][(t * 16 + col) * 64];
      kf[t][0] = *(const bf16x8*)(kp + swz * 8);
      kf[t][1] = *(const bf16x8*)(kp + (swz ^ 4) * 8);
    }

    // S^T: lane holds keys t*16+quad*4+r for q-row col -> packed b64 write
#pragma unroll
    for (int g = 0; g < 2; g++)
#pragma unroll
      for (int t = 0; t < 4; t++) {
        floatx4 z = floatx4{0.f, 0.f, 0.f, 0.f};
        z = __builtin_amdgcn_mfma_f32_16x16x32_bf16(kf[t][0], qf[g][0], z, 0, 0, 0);
        z = __builtin_amdgcn_mfma_f32_16x16x32_bf16(kf[t][1], qf[g][1], z, 0, 0, 0);
        short4v pk;
#pragma unroll
        for (int r = 0; r < 4; r++) pk[r] = f2bf_fast(EXP2(z[r]));
        *(short4v*)&P[wave][g][col][t * 16 + quad * 4] = pk;
      }

    bf16x8 pf[2][2];
#pragma unroll
    for (int g = 0; g < 2; g++)
#pragma unroll
      for (int kk = 0; kk < 2; kk++)
        pf[g][kk] = *(const bf16x8*)&P[wave][g][col][kk * 32 + quad * 8];

    bf16x8 wf[2];
#pragma unroll
    for (int kk = 0; kk < 2; kk++)
      wf[kk] = *(const bf16x8*)&Ws[kt + kk * 32 + quad * 8];  // broadcast read

#pragma unroll
    for (int g = 0; g < 2; g++) {
      rsacc[g] = __builtin_amdgcn_mfma_f32_16x16x32_bf16(wf[0], pf[g][0], rsacc[g], 0, 0, 0);
      rsacc[g] = __builtin_amdgcn_mfma_f32_16x16x32_bf16(wf[1], pf[g][1], rsacc[g], 0, 0, 0);
    }
#pragma unroll
    for (int d = 0; d < 4; d++) {
      const short* vp = &Vs[buf][(d * 16 + col) * 64];
      const bf16x8 vf0 = *(const bf16x8*)(vp + swz * 8);
      const bf16x8 vf1 = *(const bf16x8*)(vp + (swz ^ 4) * 8);
#pragma unroll
      for (int g = 0; g < 2; g++) {
        acc[g][d] = __builtin_amdgcn_mfma_f32_16x16x32_bf16(vf0, pf[g][0], acc[g][d], 0, 0, 0);
        acc[g][d] = __builtin_amdgcn_mfma_f32_16x16x32_bf16(vf1, pf[g][1], acc[g][d], 0, 0, 0);
      }
    }
    __syncthreads();  // compute reads done; next staging landed
  }

  // epilogue: ctx^T in regs -> lane col is q-row, hd = d*16 + quad*4 + r
#pragma unroll
  for (int g = 0; g < 2; g++) {
    const float inv = 1.0f / (rsacc[g][0] + 1e-30f);
    const size_t row = (size_t)b * S_ + q0 + g * 16 + col;
#pragma unroll
    for (int d = 0; d < 4; d++) {
      short4v o;
#pragma unroll
      for (int r = 0; r < 4; r++) o[r] = f2bf(acc[g][d][r] * inv);
      *(short4v*)(ctx + row * D_ + h * HD_ + d * 16 + quad * 4) = o;
    }
  }
}

// ---------------- output projection: 64x128 tile, grid 512 (2 blocks/CU) ----
__global__ __launch_bounds__(256, 2)
void gemm_out(const short* __restrict__ X, const short* __restrict__ WT,
              const float* __restrict__ ob, float* __restrict__ out) {
  __shared__ __align__(16) short As[64 * 32];    // 4 KB
  __shared__ __align__(16) short Bs[128 * 32];   // 8 KB
  const int tid = threadIdx.x;
  const int wave = tid >> 6, lane = tid & 63;
  const int col = lane & 15, quad = lane >> 4;
  const int m0 = blockIdx.x * 64;
  const int n0 = blockIdx.y * 128;
  const short* Bsrc = WT + (size_t)n0 * D_;
  const int wrow = (wave & 1) * 32;
  const int wcol = (wave >> 1) * 64;

  floatx4 acc[2][4];
#pragma unroll
  for (int i = 0; i < 2; i++)
#pragma unroll
    for (int j = 0; j < 4; j++) acc[i][j] = floatx4{0.f, 0.f, 0.f, 0.f};

  const int arow = tid >> 2, akcol = (tid & 3) * 8;
  const short* ga = X + (size_t)(m0 + arow) * D_ + akcol;
  const short* gb = Bsrc + (size_t)arow * D_ + akcol;
  short* la = As + tid * 8;
  short* lb = Bs + tid * 8;

  for (int k0 = 0; k0 < D_; k0 += 32) {
    gld_lds16(ga, la);
    gld_lds16(gb, lb);
    gld_lds16(gb + 64 * D_, lb + 2048);
    ga += 32; gb += 32;
    __syncthreads();
    bf16x8 af[2], bfr[4];
#pragma unroll
    for (int i = 0; i < 2; i++)
      af[i] = *(const bf16x8*)(As + (wrow + i * 16 + col) * 32 + quad * 8);
#pragma unroll
    for (int j = 0; j < 4; j++)
      bfr[j] = *(const bf16x8*)(Bs + (wcol + j * 16 + col) * 32 + quad * 8);
#pragma unroll
    for (int i = 0; i < 2; i++)
#pragma unroll
      for (int j = 0; j < 4; j++)
        acc[i][j] = __builtin_amdgcn_mfma_f32_16x16x32_bf16(af[i], bfr[j],
                                                            acc[i][j], 0, 0, 0);
    __syncthreads();
  }

  float bv[4];
#pragma unroll
  for (int j = 0; j < 4; j++) bv[j] = ob[n0 + wcol + j * 16 + col];

#pragma unroll
  for (int i = 0; i < 2; i++) {
    const int m = m0 + wrow + i * 16 + quad * 4;
#pragma unroll
    for (int j = 0; j < 4; j++) {
      const int n = n0 + wcol + j * 16 + col;
#pragma unroll
      for (int r = 0; r < 4; r++)
        out[(size_t)(m + r) * D_ + n] = acc[i][j][r] + bv[j];
    }
  }
}

extern "C" void kernel_launch(void* const* d_in, const int* in_sizes, int n_in,
                              void* d_out, int out_size, void* d_ws, size_t ws_size,
                              hipStream_t stream) {
  (void)in_sizes; (void)n_in; (void)out_size; (void)ws_size;
  const float* hs  = (const float*)d_in[0];
  const float* msk = (const float*)d_in[1];
  const float* qw  = (const float*)d_in[2];
  const float* qb  = (const float*)d_in[3];
  const float* kw  = (const float*)d_in[4];
  const float* kb  = (const float*)d_in[5];
  const float* vw  = (const float*)d_in[6];
  const float* vb  = (const float*)d_in[7];
  const float* ow  = (const float*)d_in[8];
  const float* ob  = (const float*)d_in[9];
  float* out = (float*)d_out;
  char* ws = (char*)d_ws;

  short* Xb  = (short*)(ws);                    // bf16 hs (8 MB); reused as Ctx
  short* WT  = (short*)(ws + (8ull  << 20));    // 4 x 1024x1024 bf16 (8 MB)
  short* Qp  = (short*)(ws + (16ull << 20));    // [B,H,S,HD] (8 MB)
  short* Kp  = (short*)(ws + (24ull << 20));    // [B,H,S,HD] (8 MB)
  short* Vtp = (short*)(ws + (32ull << 20));    // [B,H,HD,S] (8 MB)
  short* Ctx = Xb;                              // [B,S,D] bf16 (overlays Xb)

  prep<<<dim3(16, 16, 5), 256, 0, stream>>>(qw, kw, vw, ow, hs, WT, Xb);
  gemm_qkv<<<dim3(32, 24), 256, 0, stream>>>(Xb, WT, qb, kb, vb, msk, Qp, Kp, Vtp);
  attn<<<dim3(512), 256, 0, stream>>>(Qp, Kp, Vtp, msk, Ctx);
  gemm_out<<<dim3(64, 8), 256, 0, stream>>>(Ctx, WT + 3ull * D_ * D_, ob, out);
}